// Round 1
// baseline (1316.416 us; speedup 1.0000x reference)
//
#include <hip/hip_runtime.h>
#include <hip/hip_bf16.h>

using bf16 = __hip_bfloat16;
typedef __attribute__((ext_vector_type(8))) short short8v;
typedef __attribute__((ext_vector_type(4))) float float4v;

#define B_SZ 1024
#define T_SZ 16
#define V_SZ 8000
#define E_SZ 256
#define H_SZ 512
#define KSTEP 768          // E + H
#define NSTEP 2048         // 4 * H (r,z,n,hn interleaved per h)
#define NROWS (B_SZ * T_SZ)  // 16384
#define NTILES_V 63

typedef const __attribute__((address_space(1))) void* gas_ptr;
typedef __attribute__((address_space(3))) void* las_ptr;

__device__ __forceinline__ void async16(void* lds, const void* g) {
  __builtin_amdgcn_global_load_lds((gas_ptr)g, (las_ptr)lds, 16, 0, 0);
}

// ---------------------------------------------------------------------------
// Prep: bf16 casts + fused/interleaved gate weight matrix + bias + h0 init
// ---------------------------------------------------------------------------
__global__ __launch_bounds__(256) void prep_kernel(
    const float* __restrict__ ctx, const float* __restrict__ embed,
    const float* __restrict__ W_ih, const float* __restrict__ W_hh,
    const float* __restrict__ b_ih, const float* __restrict__ b_hh,
    const float* __restrict__ outW,
    bf16* __restrict__ Wbig, float* __restrict__ biasB,
    bf16* __restrict__ embB, bf16* __restrict__ outWB,
    bf16* __restrict__ ctxB, float* __restrict__ hF)
{
  const int total = 2048*768 + 2048 + 8000*256 + 8000*512 + 1024*512 + 1024*512;
  int i = blockIdx.x * 256 + threadIdx.x;
  if (i >= total) return;
  int idx = i;
  if (idx < 2048*768) {
    int n = idx / 768, k = idx % 768;
    int h = n >> 2, g = n & 3;
    float v;
    if (g < 3) v = (k < E_SZ) ? W_ih[(g*H_SZ + h)*E_SZ + k]
                              : W_hh[(g*H_SZ + h)*H_SZ + (k - E_SZ)];
    else       v = (k < E_SZ) ? 0.f
                              : W_hh[(2*H_SZ + h)*H_SZ + (k - E_SZ)];
    Wbig[idx] = __float2bfloat16(v);
    return;
  }
  idx -= 2048*768;
  if (idx < 2048) {
    int h = idx >> 2, g = idx & 3;
    biasB[idx] = (g < 3) ? (b_ih[g*H_SZ + h] + b_hh[g*H_SZ + h]) : b_hh[2*H_SZ + h];
    return;
  }
  idx -= 2048;
  if (idx < 8000*256) { embB[idx] = __float2bfloat16(embed[idx]); return; }
  idx -= 8000*256;
  if (idx < 8000*512) { outWB[idx] = __float2bfloat16(outW[idx]); return; }
  idx -= 8000*512;
  if (idx < 1024*512) { ctxB[idx] = __float2bfloat16(ctx[idx]); return; }
  idx -= 1024*512;
  hF[idx] = ctx[idx];
}

// ---------------------------------------------------------------------------
// One GRU step: gates = [x_t | h_{t-1}] @ Wbig^T  (M=1024,N=2048,K=768)
// fused gate epilogue -> h_t (f32 master + bf16 into Hist[b*T+t])
// ---------------------------------------------------------------------------
__global__ __launch_bounds__(256) void step_kernel(
    const bf16* __restrict__ Wbig, const float* __restrict__ biasB,
    const bf16* __restrict__ embB, const int* __restrict__ tok,
    const bf16* __restrict__ ctxB, bf16* __restrict__ hist,
    float* __restrict__ hF, int t)
{
  __shared__ bf16 As[128*32];
  __shared__ bf16 Bs[128*32];
  __shared__ bf16 Cs[128*132];

  const int tid = threadIdx.x;
  const int lane = tid & 63, wave = tid >> 6;
  const int m0 = blockIdx.x * 128;   // batch base
  const int n0 = blockIdx.y * 128;   // gate-col base (= h0*4)
  const int mw = (wave & 1) * 64, nw = (wave >> 1) * 64;

  float4v acc[4][4];
#pragma unroll
  for (int i = 0; i < 4; i++)
#pragma unroll
    for (int j = 0; j < 4; j++) acc[i][j] = (float4v){0.f, 0.f, 0.f, 0.f};

  const bf16* hsrc = (t == 0) ? ctxB : (hist + (size_t)(t - 1) * H_SZ);
  const size_t hstride = (t == 0) ? (size_t)H_SZ : (size_t)T_SZ * H_SZ;

  for (int kc = 0; kc < KSTEP; kc += 32) {
    // stage A (gathered [x|h]) and B (Wbig tile), 128x32 bf16 each
#pragma unroll
    for (int p = 0; p < 2; p++) {
      int flat = (p * 256 + tid) * 8;
      int r = flat >> 5, c = flat & 31;
      const bf16* srcA;
      if (kc < E_SZ) {
        int tk = (t == 0) ? 0 : tok[(m0 + r) * T_SZ + (t - 1)];
        srcA = embB + (size_t)tk * E_SZ + kc + c;
      } else {
        srcA = hsrc + (size_t)(m0 + r) * hstride + (kc - E_SZ) + c;
      }
      async16(&As[flat], srcA);
      async16(&Bs[flat], Wbig + (size_t)(n0 + r) * KSTEP + kc + c);
    }
    __syncthreads();
    short8v a[4], b[4];
#pragma unroll
    for (int i = 0; i < 4; i++)
      a[i] = *(const short8v*)&As[(mw + i * 16 + (lane & 15)) * 32 + (lane >> 4) * 8];
#pragma unroll
    for (int j = 0; j < 4; j++)
      b[j] = *(const short8v*)&Bs[(nw + j * 16 + (lane & 15)) * 32 + (lane >> 4) * 8];
#pragma unroll
    for (int i = 0; i < 4; i++)
#pragma unroll
      for (int j = 0; j < 4; j++)
        acc[i][j] = __builtin_amdgcn_mfma_f32_16x16x32_bf16(a[i], b[j], acc[i][j], 0, 0, 0);
    __syncthreads();
  }

  // dump C tile (bf16) to LDS for cross-lane gate math
#pragma unroll
  for (int i = 0; i < 4; i++)
#pragma unroll
    for (int j = 0; j < 4; j++)
#pragma unroll
      for (int r = 0; r < 4; r++) {
        int row = mw + i * 16 + ((lane >> 4) << 2) + r;
        int col = nw + j * 16 + (lane & 15);
        Cs[row * 132 + col] = __float2bfloat16(acc[i][j][r]);
      }
  __syncthreads();

  // gate math: 128 b-rows x 32 h-units
  for (int p = 0; p < 16; p++) {
    int idx = p * 256 + tid;
    int h = idx & 31, brow = idx >> 5;
    int bg = m0 + brow;
    int hg = (n0 >> 2) + h;
    const bf16* cp = &Cs[brow * 132 + h * 4];
    const float* bp = &biasB[n0 + h * 4];
    float c0 = __bfloat162float(cp[0]) + bp[0];
    float c1 = __bfloat162float(cp[1]) + bp[1];
    float c2 = __bfloat162float(cp[2]) + bp[2];
    float c3 = __bfloat162float(cp[3]) + bp[3];
    float r = 1.f / (1.f + __expf(-c0));
    float z = 1.f / (1.f + __expf(-c1));
    float n = tanhf(c2 + (r - 1.f) * c3);
    float hp = hF[(size_t)bg * H_SZ + hg];
    float hnew = (1.f - z) * n + z * hp;
    hF[(size_t)bg * H_SZ + hg] = hnew;
    hist[((size_t)bg * T_SZ + t) * H_SZ + hg] = __float2bfloat16(hnew);
  }
}

// ---------------------------------------------------------------------------
// Logits GEMM: Hist(16384x512) @ outW^T(8000x512) -> d_out (f32 logits)
// plus per-(row, n-tile) max / sumexp partials
// ---------------------------------------------------------------------------
__global__ __launch_bounds__(256) void logits_kernel(
    const bf16* __restrict__ hist, const bf16* __restrict__ outWB,
    const float* __restrict__ outb, float* __restrict__ out,
    float* __restrict__ pmax, float* __restrict__ psum)
{
  __shared__ bf16 As[128*32];
  __shared__ bf16 Bs[128*32];
  __shared__ float redM[128][2];
  __shared__ float redS[128][2];

  const int tid = threadIdx.x;
  const int lane = tid & 63, wave = tid >> 6;
  const int nt = blockIdx.x;           // 0..62
  const int m0 = blockIdx.y * 128;
  const int n0 = nt * 128;
  const int mw = (wave & 1) * 64, nw = (wave >> 1) * 64;

  float4v acc[4][4];
#pragma unroll
  for (int i = 0; i < 4; i++)
#pragma unroll
    for (int j = 0; j < 4; j++) acc[i][j] = (float4v){0.f, 0.f, 0.f, 0.f};

  for (int kc = 0; kc < H_SZ; kc += 32) {
#pragma unroll
    for (int p = 0; p < 2; p++) {
      int flat = (p * 256 + tid) * 8;
      int r = flat >> 5, c = flat & 31;
      async16(&As[flat], hist + (size_t)(m0 + r) * H_SZ + kc + c);
      int nr = n0 + r; if (nr > V_SZ - 1) nr = V_SZ - 1;
      async16(&Bs[flat], outWB + (size_t)nr * H_SZ + kc + c);
    }
    __syncthreads();
    short8v a[4], b[4];
#pragma unroll
    for (int i = 0; i < 4; i++)
      a[i] = *(const short8v*)&As[(mw + i * 16 + (lane & 15)) * 32 + (lane >> 4) * 8];
#pragma unroll
    for (int j = 0; j < 4; j++)
      b[j] = *(const short8v*)&Bs[(nw + j * 16 + (lane & 15)) * 32 + (lane >> 4) * 8];
#pragma unroll
    for (int i = 0; i < 4; i++)
#pragma unroll
      for (int j = 0; j < 4; j++)
        acc[i][j] = __builtin_amdgcn_mfma_f32_16x16x32_bf16(a[i], b[j], acc[i][j], 0, 0, 0);
    __syncthreads();
  }

  const float NEG = -1e30f;
  float ob[4]; bool valid[4];
#pragma unroll
  for (int j = 0; j < 4; j++) {
    int n = n0 + nw + j * 16 + (lane & 15);
    valid[j] = (n < V_SZ);
    ob[j] = valid[j] ? outb[n] : 0.f;
  }

  float m_[4][4], s_[4][4];
#pragma unroll
  for (int i = 0; i < 4; i++)
#pragma unroll
    for (int r = 0; r < 4; r++) { m_[i][r] = NEG; s_[i][r] = 0.f; }

#pragma unroll
  for (int i = 0; i < 4; i++) {
    int row = m0 + mw + i * 16 + ((lane >> 4) << 2);
#pragma unroll
    for (int j = 0; j < 4; j++) {
      int n = n0 + nw + j * 16 + (lane & 15);
#pragma unroll
      for (int r = 0; r < 4; r++) {
        float v = acc[i][j][r] + ob[j];
        acc[i][j][r] = v;
        if (valid[j]) {
          out[(size_t)(row + r) * V_SZ + n] = v;
          m_[i][r] = fmaxf(m_[i][r], v);
        }
      }
    }
  }
  // row-max across the 16 lanes of each quad group
#pragma unroll
  for (int i = 0; i < 4; i++)
#pragma unroll
    for (int r = 0; r < 4; r++) {
#pragma unroll
      for (int d = 1; d < 16; d <<= 1)
        m_[i][r] = fmaxf(m_[i][r], __shfl_xor(m_[i][r], d));
    }
#pragma unroll
  for (int i = 0; i < 4; i++)
#pragma unroll
    for (int j = 0; j < 4; j++)
#pragma unroll
      for (int r = 0; r < 4; r++)
        if (valid[j]) s_[i][r] += __expf(acc[i][j][r] - m_[i][r]);
#pragma unroll
  for (int i = 0; i < 4; i++)
#pragma unroll
    for (int r = 0; r < 4; r++) {
#pragma unroll
      for (int d = 1; d < 16; d <<= 1)
        s_[i][r] += __shfl_xor(s_[i][r], d);
    }
  if ((lane & 15) == 0) {
#pragma unroll
    for (int i = 0; i < 4; i++)
#pragma unroll
      for (int r = 0; r < 4; r++) {
        int rl = mw + i * 16 + ((lane >> 4) << 2) + r;
        redM[rl][nw >> 6] = m_[i][r];
        redS[rl][nw >> 6] = s_[i][r];
      }
  }
  __syncthreads();
  if (tid < 128) {
    float M0v = redM[tid][0], M1v = redM[tid][1];
    float S0v = redS[tid][0], S1v = redS[tid][1];
    float M = fmaxf(M0v, M1v);
    float S = S0v * __expf(M0v - M) + S1v * __expf(M1v - M);
    pmax[(size_t)nt * NROWS + m0 + tid] = M;
    psum[(size_t)nt * NROWS + m0 + tid] = S;
  }
}

// ---------------------------------------------------------------------------
// LSE reduce over the 63 column tiles per row
// ---------------------------------------------------------------------------
__global__ __launch_bounds__(256) void lse_kernel(
    const float* __restrict__ pmax, const float* __restrict__ psum,
    float* __restrict__ lse)
{
  int r = blockIdx.x * 256 + threadIdx.x;
  if (r >= NROWS) return;
  float M = -1e30f, S = 0.f;
  for (int c = 0; c < NTILES_V; c++) {
    float m = pmax[(size_t)c * NROWS + r];
    float s = psum[(size_t)c * NROWS + r];
    if (m > M) { S = S * __expf(M - m) + s; M = m; }
    else       { S += s * __expf(m - M); }
  }
  lse[r] = M + logf(S);
}

// ---------------------------------------------------------------------------
// logp = logit - lse[row], in place, float4
// ---------------------------------------------------------------------------
__global__ __launch_bounds__(256) void sub_kernel(
    float* __restrict__ out, const float* __restrict__ lse)
{
  const int total4 = B_SZ * T_SZ * V_SZ / 4;  // 32,768,000
  int i = blockIdx.x * 256 + threadIdx.x;
  if (i >= total4) return;
  float4 v = ((float4*)out)[i];
  int row = (i * 4) / V_SZ;
  float l = lse[row];
  v.x -= l; v.y -= l; v.z -= l; v.w -= l;
  ((float4*)out)[i] = v;
}

// ---------------------------------------------------------------------------
extern "C" void kernel_launch(void* const* d_in, const int* in_sizes, int n_in,
                              void* d_out, int out_size, void* d_ws, size_t ws_size,
                              hipStream_t stream)
{
  const float* ctx   = (const float*)d_in[0];
  const int*   tok   = (const int*)d_in[1];
  const float* embed = (const float*)d_in[2];
  const float* W_ih  = (const float*)d_in[3];
  const float* W_hh  = (const float*)d_in[4];
  const float* b_ih  = (const float*)d_in[5];
  const float* b_hh  = (const float*)d_in[6];
  const float* outW  = (const float*)d_in[7];
  const float* outb  = (const float*)d_in[8];
  float* out = (float*)d_out;

  char* base = (char*)d_ws;
  size_t o = 0;
  auto take = [&](size_t nbytes) -> void* {
    void* r = base + o;
    o = (o + nbytes + 255) & ~(size_t)255;
    return r;
  };
  bf16*  Wbig  = (bf16*) take((size_t)NSTEP * KSTEP * 2);
  float* biasB = (float*)take((size_t)NSTEP * 4);
  bf16*  embB  = (bf16*) take((size_t)V_SZ * E_SZ * 2);
  bf16*  outWB = (bf16*) take((size_t)V_SZ * H_SZ * 2);
  bf16*  ctxB  = (bf16*) take((size_t)B_SZ * H_SZ * 2);
  float* hF    = (float*)take((size_t)B_SZ * H_SZ * 4);
  bf16*  hist  = (bf16*) take((size_t)NROWS * H_SZ * 2);
  float* pmax  = (float*)take((size_t)NTILES_V * NROWS * 4);
  float* psum  = (float*)take((size_t)NTILES_V * NROWS * 4);
  float* lse   = (float*)take((size_t)NROWS * 4);

  {
    int total = 2048*768 + 2048 + 8000*256 + 8000*512 + 1024*512 + 1024*512;
    prep_kernel<<<(total + 255) / 256, 256, 0, stream>>>(
        ctx, embed, W_ih, W_hh, b_ih, b_hh, outW,
        Wbig, biasB, embB, outWB, ctxB, hF);
  }
  for (int t = 0; t < T_SZ; t++) {
    step_kernel<<<dim3(8, 16), 256, 0, stream>>>(
        Wbig, biasB, embB, tok, ctxB, hist, hF, t);
  }
  logits_kernel<<<dim3(NTILES_V, NROWS / 128), 256, 0, stream>>>(
      hist, outWB, outb, out, pmax, psum);
  lse_kernel<<<(NROWS + 255) / 256, 256, 0, stream>>>(pmax, psum, lse);
  {
    int total4 = B_SZ * T_SZ * V_SZ / 4;
    sub_kernel<<<(total4 + 255) / 256, 256, 0, stream>>>(out, lse);
  }
}

// Round 2
// 1114.904 us; speedup vs baseline: 1.1807x; 1.1807x over previous
//
#include <hip/hip_runtime.h>
#include <hip/hip_bf16.h>

using bf16 = __hip_bfloat16;
typedef __attribute__((ext_vector_type(8))) short short8v;
typedef __attribute__((ext_vector_type(4))) float float4v;

#define B_SZ 1024
#define T_SZ 16
#define V_SZ 8000
#define E_SZ 256
#define H_SZ 512
#define KW 768             // Wbig row length (E | H)
#define NSTEP 2048         // 4 * H, gates interleaved [r,z,n,hn] per h
#define NROWS (B_SZ * T_SZ)  // 16384
#define NTILES_V 63
#define LPAD 8064          // padded logits width (63*128)

typedef const __attribute__((address_space(1))) void* gas_ptr;
typedef __attribute__((address_space(3))) void* las_ptr;

__device__ __forceinline__ void async16(void* lds, const void* g) {
  __builtin_amdgcn_global_load_lds((gas_ptr)g, (las_ptr)lds, 16, 0, 0);
}

__device__ __forceinline__ float bfu2f(unsigned short u) {
  unsigned int x = ((unsigned int)u) << 16;
  return __uint_as_float(x);
}

// ---------------------------------------------------------------------------
// Prep: Wbig (gate-interleaved [W_ih|W_hh]), biasB, X gather (shifted tokens),
// outW/ctx bf16 casts, h0 = ctx f32
// ---------------------------------------------------------------------------
__global__ __launch_bounds__(256) void prep_kernel(
    const float* __restrict__ ctx, const int* __restrict__ tok,
    const float* __restrict__ embed,
    const float* __restrict__ W_ih, const float* __restrict__ W_hh,
    const float* __restrict__ b_ih, const float* __restrict__ b_hh,
    const float* __restrict__ outW,
    bf16* __restrict__ Wbig, float* __restrict__ biasB,
    bf16* __restrict__ X, bf16* __restrict__ outWB,
    bf16* __restrict__ ctxB, float* __restrict__ hF)
{
  const int N1 = NSTEP * KW;       // Wbig
  const int N2 = NSTEP;            // biasB
  const int N3 = NROWS * E_SZ;     // X
  const int N4 = V_SZ * H_SZ;      // outWB
  const int N5 = B_SZ * H_SZ;      // ctxB
  const int N6 = B_SZ * H_SZ;      // hF
  int idx = blockIdx.x * 256 + threadIdx.x;
  if (idx < N1) {
    int n = idx / KW, k = idx % KW;
    int h = n >> 2, g = n & 3;
    float v;
    if (g < 3) v = (k < E_SZ) ? W_ih[(g*H_SZ + h)*E_SZ + k]
                              : W_hh[(g*H_SZ + h)*H_SZ + (k - E_SZ)];
    else       v = (k < E_SZ) ? 0.f
                              : W_hh[(2*H_SZ + h)*H_SZ + (k - E_SZ)];
    Wbig[idx] = __float2bfloat16(v);
    return;
  }
  idx -= N1;
  if (idx < N2) {
    int h = idx >> 2, g = idx & 3;
    biasB[idx] = (g < 3) ? (b_ih[g*H_SZ + h] + b_hh[g*H_SZ + h]) : b_hh[2*H_SZ + h];
    return;
  }
  idx -= N2;
  if (idx < N3) {
    int e = idx & (E_SZ - 1);
    int rb = idx >> 8;             // t*B + b
    int t = rb >> 10, b = rb & (B_SZ - 1);
    int tk = (t == 0) ? 0 : tok[b * T_SZ + (t - 1)];
    X[idx] = __float2bfloat16(embed[(size_t)tk * E_SZ + e]);
    return;
  }
  idx -= N3;
  if (idx < N4) { outWB[idx] = __float2bfloat16(outW[idx]); return; }
  idx -= N4;
  if (idx < N5) { ctxB[idx] = __float2bfloat16(ctx[idx]); return; }
  idx -= N5;
  if (idx < N6) hF[idx] = ctx[idx];
}

// ---------------------------------------------------------------------------
// Gi = X(16384x256) @ Wbig[:, 0:256]^T + biasB  -> f32 (t*B+b, 2048)
// ---------------------------------------------------------------------------
__global__ __launch_bounds__(256) void gi_kernel(
    const bf16* __restrict__ X, const bf16* __restrict__ Wbig,
    const float* __restrict__ biasB, float* __restrict__ Gi)
{
  __shared__ bf16 As[128*32];
  __shared__ bf16 Bs[128*32];
  const int tid = threadIdx.x;
  const int lane = tid & 63, wave = tid >> 6;
  const int m0 = blockIdx.x * 128;
  const int n0 = blockIdx.y * 128;
  const int mw = (wave & 1) * 64, nw = (wave >> 1) * 64;

  float4v acc[4][4];
#pragma unroll
  for (int i = 0; i < 4; i++)
#pragma unroll
    for (int j = 0; j < 4; j++) acc[i][j] = (float4v){0.f, 0.f, 0.f, 0.f};

  for (int kc = 0; kc < E_SZ; kc += 32) {
#pragma unroll
    for (int p = 0; p < 2; p++) {
      int flat = (p * 256 + tid) * 8;
      int r = flat >> 5, c = flat & 31;
      async16(&As[flat], X + (size_t)(m0 + r) * E_SZ + kc + c);
      async16(&Bs[flat], Wbig + (size_t)(n0 + r) * KW + kc + c);
    }
    __syncthreads();
    short8v a[4], b[4];
#pragma unroll
    for (int i = 0; i < 4; i++)
      a[i] = *(const short8v*)&As[(mw + i * 16 + (lane & 15)) * 32 + (lane >> 4) * 8];
#pragma unroll
    for (int j = 0; j < 4; j++)
      b[j] = *(const short8v*)&Bs[(nw + j * 16 + (lane & 15)) * 32 + (lane >> 4) * 8];
#pragma unroll
    for (int i = 0; i < 4; i++)
#pragma unroll
      for (int j = 0; j < 4; j++)
        acc[i][j] = __builtin_amdgcn_mfma_f32_16x16x32_bf16(a[i], b[j], acc[i][j], 0, 0, 0);
    __syncthreads();
  }
#pragma unroll
  for (int j = 0; j < 4; j++) {
    int n = n0 + nw + j * 16 + (lane & 15);
    float bias = biasB[n];
#pragma unroll
    for (int i = 0; i < 4; i++) {
      int row = m0 + mw + i * 16 + ((lane >> 4) << 2);
#pragma unroll
      for (int r = 0; r < 4; r++)
        Gi[(size_t)(row + r) * NSTEP + n] = acc[i][j][r] + bias;
    }
  }
}

// ---------------------------------------------------------------------------
// Step t: Gh = h_{t-1}(1024x512) @ Wbig[:,256:768]^T, tile 64x128, grid 16x16
// epilogue: c_g = Gi_g + Gh_g; gate math -> hF (f32) + hist (bf16)
// ---------------------------------------------------------------------------
__global__ __launch_bounds__(256) void step_kernel(
    const bf16* __restrict__ Wbig, const float* __restrict__ Gi,
    const bf16* __restrict__ ctxB, bf16* __restrict__ hist,
    float* __restrict__ hF, int t)
{
  __shared__ bf16 As[64*32];
  __shared__ bf16 Bs[128*32];
  __shared__ float Cs[64*132];

  const int tid = threadIdx.x;
  const int lane = tid & 63, wave = tid >> 6;
  const int m0 = blockIdx.x * 64;    // batch base
  const int n0 = blockIdx.y * 128;   // gate-col base (= h0*4)

  float4v acc[4][2];
#pragma unroll
  for (int i = 0; i < 4; i++)
#pragma unroll
    for (int j = 0; j < 2; j++) acc[i][j] = (float4v){0.f, 0.f, 0.f, 0.f};

  const bf16* hsrc = (t == 0) ? (ctxB + (size_t)m0 * H_SZ)
                              : (hist + ((size_t)m0 * T_SZ + (t - 1)) * H_SZ);
  const size_t hstride = (t == 0) ? (size_t)H_SZ : (size_t)T_SZ * H_SZ;

  for (int kc = 0; kc < H_SZ; kc += 32) {
    {
      int flat = tid * 8;
      int r = flat >> 5, c = flat & 31;
      async16(&As[flat], hsrc + (size_t)r * hstride + kc + c);
    }
#pragma unroll
    for (int p = 0; p < 2; p++) {
      int flat = (p * 256 + tid) * 8;
      int r = flat >> 5, c = flat & 31;
      async16(&Bs[flat], Wbig + (size_t)(n0 + r) * KW + E_SZ + kc + c);
    }
    __syncthreads();
    short8v a[4], b[2];
#pragma unroll
    for (int i = 0; i < 4; i++)
      a[i] = *(const short8v*)&As[(i * 16 + (lane & 15)) * 32 + (lane >> 4) * 8];
#pragma unroll
    for (int j = 0; j < 2; j++)
      b[j] = *(const short8v*)&Bs[(wave * 32 + j * 16 + (lane & 15)) * 32 + (lane >> 4) * 8];
#pragma unroll
    for (int i = 0; i < 4; i++)
#pragma unroll
      for (int j = 0; j < 2; j++)
        acc[i][j] = __builtin_amdgcn_mfma_f32_16x16x32_bf16(a[i], b[j], acc[i][j], 0, 0, 0);
    __syncthreads();
  }

  // dump Gh tile (f32) to LDS for cross-lane gate math
#pragma unroll
  for (int i = 0; i < 4; i++)
#pragma unroll
    for (int j = 0; j < 2; j++)
#pragma unroll
      for (int r = 0; r < 4; r++) {
        int row = i * 16 + ((lane >> 4) << 2) + r;
        int col = wave * 32 + j * 16 + (lane & 15);
        Cs[row * 132 + col] = acc[i][j][r];
      }
  __syncthreads();

  // gate math: 64 b-rows x 32 h-units
#pragma unroll
  for (int p = 0; p < 8; p++) {
    int idx = p * 256 + tid;
    int h = idx & 31, brow = idx >> 5;
    int bg = m0 + brow;
    int hg = (n0 >> 2) + h;
    const float4* gi4 = (const float4*)&Gi[((size_t)t * B_SZ + bg) * NSTEP + n0 + h * 4];
    float4 g = *gi4;
    const float4* ch4 = (const float4*)&Cs[brow * 132 + h * 4];
    float4 ch = *ch4;
    float c0 = g.x + ch.x;
    float c1 = g.y + ch.y;
    float c2 = g.z + ch.z;
    float c3 = g.w + ch.w;
    float r_ = 1.f / (1.f + __expf(-c0));
    float z  = 1.f / (1.f + __expf(-c1));
    float n  = tanhf(c2 + (r_ - 1.f) * c3);
    float hp = hF[(size_t)bg * H_SZ + hg];
    float hnew = (1.f - z) * n + z * hp;
    hF[(size_t)bg * H_SZ + hg] = hnew;
    hist[((size_t)bg * T_SZ + t) * H_SZ + hg] = __float2bfloat16(hnew);
  }
}

// ---------------------------------------------------------------------------
// Logits GEMM: hist(16384x512) @ outW^T(8000x512) -> L (bf16, stride 8064)
// plus per-(row, n-tile) max / sumexp partials
// ---------------------------------------------------------------------------
__global__ __launch_bounds__(256) void logits_kernel(
    const bf16* __restrict__ hist, const bf16* __restrict__ outWB,
    const float* __restrict__ outb, bf16* __restrict__ L,
    float* __restrict__ pmax, float* __restrict__ psum)
{
  __shared__ bf16 As[128*32];
  __shared__ bf16 Bs[128*32];
  __shared__ float redM[128][2];
  __shared__ float redS[128][2];

  const int tid = threadIdx.x;
  const int lane = tid & 63, wave = tid >> 6;
  const int nt = blockIdx.x;           // 0..62
  const int m0 = blockIdx.y * 128;
  const int n0 = nt * 128;
  const int mw = (wave & 1) * 64, nw = (wave >> 1) * 64;

  float4v acc[4][4];
#pragma unroll
  for (int i = 0; i < 4; i++)
#pragma unroll
    for (int j = 0; j < 4; j++) acc[i][j] = (float4v){0.f, 0.f, 0.f, 0.f};

  for (int kc = 0; kc < H_SZ; kc += 32) {
#pragma unroll
    for (int p = 0; p < 2; p++) {
      int flat = (p * 256 + tid) * 8;
      int r = flat >> 5, c = flat & 31;
      async16(&As[flat], hist + (size_t)(m0 + r) * H_SZ + kc + c);
      int nr = n0 + r; if (nr > V_SZ - 1) nr = V_SZ - 1;
      async16(&Bs[flat], outWB + (size_t)nr * H_SZ + kc + c);
    }
    __syncthreads();
    short8v a[4], b[4];
#pragma unroll
    for (int i = 0; i < 4; i++)
      a[i] = *(const short8v*)&As[(mw + i * 16 + (lane & 15)) * 32 + (lane >> 4) * 8];
#pragma unroll
    for (int j = 0; j < 4; j++)
      b[j] = *(const short8v*)&Bs[(nw + j * 16 + (lane & 15)) * 32 + (lane >> 4) * 8];
#pragma unroll
    for (int i = 0; i < 4; i++)
#pragma unroll
      for (int j = 0; j < 4; j++)
        acc[i][j] = __builtin_amdgcn_mfma_f32_16x16x32_bf16(a[i], b[j], acc[i][j], 0, 0, 0);
    __syncthreads();
  }

  const float NEG = -1e30f;
  float ob[4]; bool valid[4];
#pragma unroll
  for (int j = 0; j < 4; j++) {
    int n = n0 + nw + j * 16 + (lane & 15);
    valid[j] = (n < V_SZ);
    ob[j] = valid[j] ? outb[n] : 0.f;
  }

  float m_[4][4], s_[4][4];
#pragma unroll
  for (int i = 0; i < 4; i++)
#pragma unroll
    for (int r = 0; r < 4; r++) { m_[i][r] = NEG; s_[i][r] = 0.f; }

#pragma unroll
  for (int i = 0; i < 4; i++) {
    int row = m0 + mw + i * 16 + ((lane >> 4) << 2);
#pragma unroll
    for (int j = 0; j < 4; j++) {
      int n = n0 + nw + j * 16 + (lane & 15);
#pragma unroll
      for (int r = 0; r < 4; r++) {
        float v = acc[i][j][r] + ob[j];
        acc[i][j][r] = v;
        L[(size_t)(row + r) * LPAD + n] = __float2bfloat16(v);
        if (valid[j]) m_[i][r] = fmaxf(m_[i][r], v);
      }
    }
  }
#pragma unroll
  for (int i = 0; i < 4; i++)
#pragma unroll
    for (int r = 0; r < 4; r++) {
#pragma unroll
      for (int d = 1; d < 16; d <<= 1)
        m_[i][r] = fmaxf(m_[i][r], __shfl_xor(m_[i][r], d));
    }
#pragma unroll
  for (int i = 0; i < 4; i++)
#pragma unroll
    for (int j = 0; j < 4; j++)
#pragma unroll
      for (int r = 0; r < 4; r++)
        if (valid[j]) s_[i][r] += __expf(acc[i][j][r] - m_[i][r]);
#pragma unroll
  for (int i = 0; i < 4; i++)
#pragma unroll
    for (int r = 0; r < 4; r++) {
#pragma unroll
      for (int d = 1; d < 16; d <<= 1)
        s_[i][r] += __shfl_xor(s_[i][r], d);
    }
  if ((lane & 15) == 0) {
#pragma unroll
    for (int i = 0; i < 4; i++)
#pragma unroll
      for (int r = 0; r < 4; r++) {
        int rl = mw + i * 16 + ((lane >> 4) << 2) + r;
        redM[rl][nw >> 6] = m_[i][r];
        redS[rl][nw >> 6] = s_[i][r];
      }
  }
  __syncthreads();
  if (tid < 128) {
    float M0v = redM[tid][0], M1v = redM[tid][1];
    float S0v = redS[tid][0], S1v = redS[tid][1];
    float M = fmaxf(M0v, M1v);
    float S = S0v * __expf(M0v - M) + S1v * __expf(M1v - M);
    pmax[(size_t)nt * NROWS + m0 + tid] = M;
    psum[(size_t)nt * NROWS + m0 + tid] = S;
  }
}

// ---------------------------------------------------------------------------
// LSE reduce over the 63 column tiles per row
// ---------------------------------------------------------------------------
__global__ __launch_bounds__(256) void lse_kernel(
    const float* __restrict__ pmax, const float* __restrict__ psum,
    float* __restrict__ lse)
{
  int r = blockIdx.x * 256 + threadIdx.x;
  if (r >= NROWS) return;
  float M = -1e30f, S = 0.f;
  for (int c = 0; c < NTILES_V; c++) {
    float m = pmax[(size_t)c * NROWS + r];
    float s = psum[(size_t)c * NROWS + r];
    if (m > M) { S = S * __expf(M - m) + s; M = m; }
    else       { S += s * __expf(m - M); }
  }
  lse[r] = M + logf(S);
}

// ---------------------------------------------------------------------------
// out = bf16_logit - lse[row], 8 elems/thread
// ---------------------------------------------------------------------------
__global__ __launch_bounds__(256) void sub_kernel(
    const unsigned short* __restrict__ L, const float* __restrict__ lse,
    float* __restrict__ out)
{
  const int total8 = NROWS * (V_SZ / 8);   // 16,384,000
  int i = blockIdx.x * 256 + threadIdx.x;
  if (i >= total8) return;
  int row = i / (V_SZ / 8);
  int c = (i - row * (V_SZ / 8)) * 8;
  float l = lse[row];
  short8v v = *(const short8v*)&L[(size_t)row * LPAD + c];
  float4 o0, o1;
  o0.x = bfu2f((unsigned short)v[0]) - l;
  o0.y = bfu2f((unsigned short)v[1]) - l;
  o0.z = bfu2f((unsigned short)v[2]) - l;
  o0.w = bfu2f((unsigned short)v[3]) - l;
  o1.x = bfu2f((unsigned short)v[4]) - l;
  o1.y = bfu2f((unsigned short)v[5]) - l;
  o1.z = bfu2f((unsigned short)v[6]) - l;
  o1.w = bfu2f((unsigned short)v[7]) - l;
  float4* op = (float4*)&out[(size_t)row * V_SZ + c];
  op[0] = o0;
  op[1] = o1;
}

// ---------------------------------------------------------------------------
extern "C" void kernel_launch(void* const* d_in, const int* in_sizes, int n_in,
                              void* d_out, int out_size, void* d_ws, size_t ws_size,
                              hipStream_t stream)
{
  const float* ctx   = (const float*)d_in[0];
  const int*   tok   = (const int*)d_in[1];
  const float* embed = (const float*)d_in[2];
  const float* W_ih  = (const float*)d_in[3];
  const float* W_hh  = (const float*)d_in[4];
  const float* b_ih  = (const float*)d_in[5];
  const float* b_hh  = (const float*)d_in[6];
  const float* outW  = (const float*)d_in[7];
  const float* outb  = (const float*)d_in[8];
  float* out = (float*)d_out;

  char* base = (char*)d_ws;
  size_t o = 0;
  auto take = [&](size_t nbytes) -> void* {
    void* r = base + o;
    o = (o + nbytes + 255) & ~(size_t)255;
    return r;
  };
  bf16*  Wbig  = (bf16*) take((size_t)NSTEP * KW * 2);
  float* biasB = (float*)take((size_t)NSTEP * 4);
  bf16*  X     = (bf16*) take((size_t)NROWS * E_SZ * 2);
  bf16*  outWB = (bf16*) take((size_t)V_SZ * H_SZ * 2);
  bf16*  ctxB  = (bf16*) take((size_t)B_SZ * H_SZ * 2);
  float* hF    = (float*)take((size_t)B_SZ * H_SZ * 4);
  bf16*  hist  = (bf16*) take((size_t)NROWS * H_SZ * 2);
  float* Gi    = (float*)take((size_t)NROWS * NSTEP * 4);
  bf16*  L     = (bf16*) take((size_t)NROWS * LPAD * 2);
  float* pmax  = (float*)take((size_t)NTILES_V * NROWS * 4);
  float* psum  = (float*)take((size_t)NTILES_V * NROWS * 4);
  float* lse   = (float*)take((size_t)NROWS * 4);

  {
    int total = NSTEP*KW + NSTEP + NROWS*E_SZ + V_SZ*H_SZ + B_SZ*H_SZ + B_SZ*H_SZ;
    prep_kernel<<<(total + 255) / 256, 256, 0, stream>>>(
        ctx, tok, embed, W_ih, W_hh, b_ih, b_hh, outW,
        Wbig, biasB, X, outWB, ctxB, hF);
  }
  gi_kernel<<<dim3(NROWS / 128, NSTEP / 128), 256, 0, stream>>>(X, Wbig, biasB, Gi);
  for (int t = 0; t < T_SZ; t++) {
    step_kernel<<<dim3(B_SZ / 64, NSTEP / 128), 256, 0, stream>>>(
        Wbig, Gi, ctxB, hist, hF, t);
  }
  logits_kernel<<<dim3(NTILES_V, NROWS / 128), 256, 0, stream>>>(
      hist, outWB, outb, L, pmax, psum);
  lse_kernel<<<(NROWS + 255) / 256, 256, 0, stream>>>(pmax, psum, lse);
  {
    int total8 = NROWS * (V_SZ / 8);
    sub_kernel<<<(total8 + 255) / 256, 256, 0, stream>>>(
        (const unsigned short*)L, lse, out);
  }
}